// Round 4
// baseline (1460.349 us; speedup 1.0000x reference)
//
#include <hip/hip_runtime.h>
#include <hip/hip_fp16.h>
#include <stdint.h>
#include <stddef.h>

// Problem constants
#define B_N   8
#define C_N   256
#define H_N   256
#define W_N   256
#define HW_N  65536
#define NSEL  6554        // int(HW*0.1)+1
#define NTOT  52432       // B*NSEL
#define NHALF 26216       // NTOT/2 (threefry counter halves)
#define LOSS_BLOCKS 512
#define TF_BLOCKS 103     // ceil(NHALF/256)
#define WAVE2_N   824     // TF_BLOCKS*4 waves * 2 entries

// ---- workspace layout (bytes) ----
static constexpr size_t OFF_BND      = 0;           // f32[B*HW]           2,097,152
static constexpr size_t OFF_HIST_HI  = 2097152;     // u32[8][4][65536]    8,388,608 (zeroed)
static constexpr size_t OFF_BUCKETA  = 10485760;    // u32[65536]            262,144 (zeroed)
static constexpr size_t OFF_RANKINFO = 10747904;    // u32[64]                   256 (zeroed)
static constexpr size_t OFF_WAVE2    = 10748160;    // u64[1024]               8,192
static constexpr size_t OFF_LAB      = 10756352;    // u8[NTOT] pad           52,480
static constexpr size_t OFF_SELPOS   = 10808832;    // u16[B*HW]           1,048,576 (fill 0xFFFF)
static constexpr size_t OFF_CNT      = 11857408;    // u32: cnt0[8], cnt1[8]
static constexpr size_t OFF_CENTERS  = 11857664;    // f32[128]
static constexpr size_t OFF_CAND     = 11858176;    // u64[2][512]
static constexpr size_t OFF_LIST0    = 11866368;    // u32[NTOT] pad         209,920
static constexpr size_t OFF_LIST1    = 12076288;    // u32[NTOT] pad         209,920
static constexpr size_t OFF_PARTIAL  = 12286208;    // f64[2048]              16,384
static constexpr size_t OFF_XG       = 12302592;    // f16[256*NTOT]      26,845,184
static constexpr size_t OFF_MASKED   = 39147776;    // f32[NTOT*64]       13,422,592 -> end 52,570,368

#define ZERO_WORDS   2162752   // HIST_HI + BUCKETA + RANKINFO (bytes/4)
#define SELPOS_WORDS 262144

// ===================== parallel block scan (1024 threads, exclusive) =====================
__device__ __forceinline__ unsigned scan1024(unsigned v, unsigned* swave, int tid){
  unsigned incl = v;
  #pragma unroll
  for (int d = 1; d < 64; d <<= 1){
    unsigned n = __shfl_up(incl, d);
    if ((tid & 63) >= d) incl += n;
  }
  if ((tid & 63) == 63) swave[tid >> 6] = incl;
  __syncthreads();
  if (tid < 16){
    unsigned w = swave[tid];
    #pragma unroll
    for (int d = 1; d < 16; d <<= 1){
      unsigned n = __shfl_up(w, d);
      if (tid >= d) w += n;
    }
    swave[tid] = w;
  }
  __syncthreads();
  unsigned woff = (tid >> 6) ? swave[(tid >> 6) - 1] : 0u;
  return woff + incl - v;
}

// ===================== init =====================
__global__ void k_init(char* ws){
  int i = blockIdx.x * 256 + threadIdx.x;
  if (i < ZERO_WORDS)   ((unsigned*)(ws + OFF_HIST_HI))[i] = 0u;
  if (i < SELPOS_WORDS) ((unsigned*)(ws + OFF_SELPOS))[i]  = 0xFFFFFFFFu;
}

// ===================== boundary map + fused hi16 histogram =====================
// block=256 (4 waves = 4 rows), grid = B*H/4 = 512. Each thread: 4 pixels via float4.
__global__ __launch_bounds__(256) void k_bnd(const float* __restrict__ Fe, float* __restrict__ bnd,
                                             unsigned* __restrict__ hist_hi){
  const int bid = blockIdx.x;
  const int b  = bid >> 6;
  const unsigned rep = bid & 3u;
  const int h  = ((bid & 63) << 2) + (threadIdx.x >> 6);
  const int tx = threadIdx.x & 63;
  const int w  = tx << 2;
  const size_t base = (size_t)b * C_N * HW_N + (size_t)h * W_N + w;
  const int hn = (h < H_N - 1) ? (h + 1) : (H_N - 2);   // replicate: gy[255]=|Fe[255]-Fe[254]|
  const ptrdiff_t roff = (ptrdiff_t)(hn - h) * W_N;
  double a0 = 0.0, a1 = 0.0, a2 = 0.0, a3 = 0.0;
  for (int c = 0; c < C_N; ++c){
    const float* p = Fe + base + (size_t)c * HW_N;
    const float4 va = *(const float4*)p;
    const float4 vg = *(const float4*)(p + roff);
    const float nx = __shfl_down(va.x, 1);
    const float gx0 = fabsf(va.y - va.x);
    const float gx1 = fabsf(va.z - va.y);
    const float gx2 = fabsf(va.w - va.z);
    const float gx3 = (tx < 63) ? fabsf(nx - va.w) : gx2;  // replicate gx[255]=gx[254]
    a0 += (double)(gx0 + fabsf(vg.x - va.x));
    a1 += (double)(gx1 + fabsf(vg.y - va.y));
    a2 += (double)(gx2 + fabsf(vg.z - va.z));
    a3 += (double)(gx3 + fabsf(vg.w - va.w));
  }
  float4 o; o.x = (float)a0; o.y = (float)a1; o.z = (float)a2; o.w = (float)a3;
  *(float4*)(bnd + (size_t)b * HW_N + (size_t)h * W_N + w) = o;
  unsigned* hh = hist_hi + (((size_t)(b * 4 + rep)) << 16);
  atomicAdd(&hh[__float_as_uint(o.x) >> 16], 1u);
  atomicAdd(&hh[__float_as_uint(o.y) >> 16], 1u);
  atomicAdd(&hh[__float_as_uint(o.z) >> 16], 1u);
  atomicAdd(&hh[__float_as_uint(o.w) >> 16], 1u);
}

// ===================== fused top-NSEL select (hi16 global / mid8 LDS / lo8 LDS) =====
// 8 blocks (one per batch) x 1024 threads. Produces selpos directly.
__global__ __launch_bounds__(1024) void k_select(const float* __restrict__ bnd,
                                                 const unsigned* __restrict__ hist_hi,
                                                 unsigned short* __restrict__ selpos){
  __shared__ unsigned sv[1024];
  __shared__ unsigned swave[16];
  __shared__ unsigned h8[256];
  __shared__ unsigned sh[6];    // hb, r, mb, r2, T, need
  const int b = blockIdx.x, t = threadIdx.x;
  const float* bb = bnd + (size_t)b * HW_N;

  // --- phase 1: hi16 threshold bucket (sum 4 replicas) ---
  unsigned sum = 0;
  #pragma unroll
  for (int r = 0; r < 4; ++r){
    const unsigned* hr = hist_hi + (((size_t)(b * 4 + r)) << 16) + t * 64;
    for (int k = 0; k < 64; k += 4){
      uint4 u = *(const uint4*)(hr + k);
      sum += u.x + u.y + u.z + u.w;
    }
  }
  sv[t] = sum; __syncthreads();
  unsigned v = sv[1023 - t];
  unsigned incl = scan1024(v, swave, t) + v;      // suffix-sum at chunk 1023-t
  if (incl >= NSEL && (incl - v) < NSEL){
    int tc = 1023 - t;
    unsigned c2 = incl - v;
    for (int k = 63; k >= 0; --k){
      unsigned hcnt = 0;
      #pragma unroll
      for (int r = 0; r < 4; ++r)
        hcnt += hist_hi[(((size_t)(b * 4 + r)) << 16) + tc * 64 + k];
      if (c2 + hcnt >= NSEL){ sh[0] = (unsigned)(tc * 64 + k); sh[1] = NSEL - c2; break; }
      c2 += hcnt;
    }
  }
  __syncthreads();
  const unsigned hb = sh[0], r1 = sh[1];

  // --- phase 2: mid8 histogram of pixels in bucket hb ---
  if (t < 256) h8[t] = 0;
  __syncthreads();
  for (int k = 0; k < 64; k += 4){
    float4 f = *(const float4*)(bb + t * 64 + k);
    unsigned kk[4] = { __float_as_uint(f.x), __float_as_uint(f.y),
                       __float_as_uint(f.z), __float_as_uint(f.w) };
    #pragma unroll
    for (int c = 0; c < 4; ++c)
      if ((kk[c] >> 16) == hb) atomicAdd(&h8[(kk[c] >> 8) & 0xFFu], 1u);
  }
  __syncthreads();
  if (t == 0){
    unsigned cum = 0;
    for (int k = 255; k >= 0; --k){
      unsigned hcnt = h8[k];
      if (cum + hcnt >= r1){ sh[2] = (unsigned)k; sh[3] = r1 - cum; break; }
      cum += hcnt;
    }
  }
  __syncthreads();
  const unsigned mb = sh[2], r2 = sh[3];
  const unsigned pref = (hb << 8) | mb;

  // --- phase 3: lo8 histogram within (hb, mb) ---
  if (t < 256) h8[t] = 0;
  __syncthreads();
  for (int k = 0; k < 64; k += 4){
    float4 f = *(const float4*)(bb + t * 64 + k);
    unsigned kk[4] = { __float_as_uint(f.x), __float_as_uint(f.y),
                       __float_as_uint(f.z), __float_as_uint(f.w) };
    #pragma unroll
    for (int c = 0; c < 4; ++c)
      if ((kk[c] >> 8) == pref) atomicAdd(&h8[kk[c] & 0xFFu], 1u);
  }
  __syncthreads();
  if (t == 0){
    unsigned cum = 0;
    for (int k = 255; k >= 0; --k){
      unsigned hcnt = h8[k];
      if (cum + hcnt >= r2){ sh[4] = (pref << 8) | (unsigned)k; sh[5] = r2 - cum; break; }
      cum += hcnt;
    }
  }
  __syncthreads();
  const unsigned T = sh[4], need = sh[5];

  // --- phase 4: ordered compaction (rank in pixel order; ties taken first-index) ---
  unsigned ng = 0, ne = 0;
  for (int k = 0; k < 64; k += 4){
    float4 f = *(const float4*)(bb + t * 64 + k);
    unsigned k0 = __float_as_uint(f.x), k1 = __float_as_uint(f.y);
    unsigned k2 = __float_as_uint(f.z), k3 = __float_as_uint(f.w);
    ng += (k0 > T) + (k1 > T) + (k2 > T) + (k3 > T);
    ne += (k0 == T) + (k1 == T) + (k2 == T) + (k3 == T);
  }
  unsigned excl = scan1024(ng | (ne << 16), swave, t);
  unsigned g = excl & 0xFFFFu, e = excl >> 16;
  for (int k = 0; k < 64; k += 4){
    float4 f = *(const float4*)(bb + t * 64 + k);
    unsigned keys[4] = { __float_as_uint(f.x), __float_as_uint(f.y),
                         __float_as_uint(f.z), __float_as_uint(f.w) };
    #pragma unroll
    for (int c = 0; c < 4; ++c){
      int p = t * 64 + k + c;
      if (keys[c] > T){
        unsigned etk = e < need ? e : need;
        selpos[(size_t)b * HW_N + p] = (unsigned short)(g + etk);
        ++g;
      } else if (keys[c] == T){
        if (e < need) selpos[(size_t)b * HW_N + p] = (unsigned short)(g + e);
        ++e;
      }
    }
  }
}

// ===================== coalesced gather Fe -> Xg[c][t] (fp16), skip unselected =====
__global__ void k_gather(const float* __restrict__ Fe, const unsigned short* __restrict__ selpos,
                         __half* __restrict__ Xg){
  const int b = blockIdx.z, c0 = blockIdx.y * 4;
  const int p = blockIdx.x * 1024 + threadIdx.x * 4;
  const ushort4 s = *(const ushort4*)(selpos + (size_t)b * HW_N + p);
  if ((unsigned short)(s.x & s.y & s.z & s.w) == 0xFFFFu) return;  // no selected pixel here
  #pragma unroll
  for (int cc = 0; cc < 4; ++cc){
    const int c = c0 + cc;
    const float4 v = *(const float4*)(Fe + ((size_t)(b * C_N + c)) * HW_N + p);
    __half* xc = Xg + (size_t)c * NTOT + (size_t)b * NSEL;
    if (s.x != 0xFFFFu) xc[s.x] = __float2half(v.x);
    if (s.y != 0xFFFFu) xc[s.y] = __float2half(v.y);
    if (s.z != 0xFFFFu) xc[s.z] = __float2half(v.z);
    if (s.w != 0xFFFFu) xc[s.w] = __float2half(v.w);
  }
}

// ===================== projection MLP at selected points =====================
__global__ __launch_bounds__(256, 2) void k_mlp(const __half* __restrict__ Xg,
    const float* __restrict__ w1, const float* __restrict__ b1,
    const float* __restrict__ w2, const float* __restrict__ b2,
    float* __restrict__ masked){
  __shared__ float xs[64 * 129];   // x chunk [pt][128], reused as h [pt][128]
  const int t0 = blockIdx.x * 64;
  const int tid = threadIdx.x;
  const int wv = __builtin_amdgcn_readfirstlane(tid >> 6);
  const int pt = tid & 63;
  const int t = t0 + pt;

  float acc[32];
  #pragma unroll
  for (int kk = 0; kk < 32; ++kk) acc[kk] = b1[wv * 32 + kk];

  for (int half = 0; half < 2; ++half){
    for (int it = 0; it < 32; ++it){
      int idx = it * 256 + tid;
      int cl = idx >> 6, ptl = idx & 63;
      int tt = t0 + ptl;
      float v = 0.f;
      if (tt < NTOT) v = __half2float(Xg[(size_t)(half * 128 + cl) * NTOT + tt]);
      xs[ptl * 129 + cl] = v;
    }
    __syncthreads();
    for (int cc = 0; cc < 128; cc += 32){
      float xr[32];
      #pragma unroll
      for (int j = 0; j < 32; ++j) xr[j] = xs[pt * 129 + cc + j];
      #pragma unroll
      for (int kk = 0; kk < 32; ++kk){
        const float* wr = w1 + (size_t)(wv * 32 + kk) * 256 + half * 128 + cc;
        float a = acc[kk];
        #pragma unroll
        for (int j = 0; j < 32; ++j) a = fmaf(wr[j], xr[j], a);
        acc[kk] = a;
      }
    }
    __syncthreads();
  }
  #pragma unroll
  for (int kk = 0; kk < 32; ++kk) xs[pt * 129 + wv * 32 + kk] = fmaxf(acc[kk], 0.f);
  __syncthreads();

  float o[16];
  #pragma unroll
  for (int ee = 0; ee < 16; ++ee) o[ee] = b2[wv * 16 + ee];
  for (int kc = 0; kc < 128; kc += 32){
    float hr[32];
    #pragma unroll
    for (int j = 0; j < 32; ++j) hr[j] = xs[pt * 129 + kc + j];
    #pragma unroll
    for (int ee = 0; ee < 16; ++ee){
      const float* wr = w2 + (size_t)(wv * 16 + ee) * 128 + kc;
      float a = o[ee];
      #pragma unroll
      for (int j = 0; j < 32; ++j) a = fmaf(wr[j], hr[j], a);
      o[ee] = a;
    }
  }
  if (t < NTOT){
    float4* mp = (float4*)(masked + (size_t)t * 64 + wv * 16);
    mp[0] = make_float4(o[0], o[1], o[2], o[3]);
    mp[1] = make_float4(o[4], o[5], o[6], o[7]);
    mp[2] = make_float4(o[8], o[9], o[10], o[11]);
    mp[3] = make_float4(o[12], o[13], o[14], o[15]);
  }
}

// ===================== threefry (jax.random.permutation(key(42), NTOT)[:2]) =====================
__device__ __forceinline__ unsigned rotl32(unsigned x, int d){ return (x << d) | (x >> (32 - d)); }

__device__ __forceinline__ void threefry(unsigned k0, unsigned k1, unsigned& x0, unsigned& x1){
  const unsigned ks2 = k0 ^ k1 ^ 0x1BD11BDAu;
  x0 += k0; x1 += k1;
#define TFR(r) { x0 += x1; x1 = rotl32(x1, r); x1 ^= x0; }
  TFR(13) TFR(15) TFR(26) TFR(6)  x0 += k1;  x1 += ks2 + 1u;
  TFR(17) TFR(29) TFR(16) TFR(24) x0 += ks2; x1 += k0 + 2u;
  TFR(13) TFR(15) TFR(26) TFR(6)  x0 += k0;  x1 += k1 + 3u;
  TFR(17) TFR(29) TFR(16) TFR(24) x0 += k1;  x1 += ks2 + 4u;
  TFR(13) TFR(15) TFR(26) TFR(6)  x0 += ks2; x1 += k0 + 5u;
#undef TFR
}

__device__ __forceinline__ void get_subkeys(unsigned& a0, unsigned& a1, unsigned& b0, unsigned& b1){
  unsigned x0 = 0u, x1 = 2u; threefry(0u, 42u, x0, x1);
  unsigned y0 = 1u, y1 = 3u; threefry(0u, 42u, y0, y1);
  a0 = x1; a1 = y1;
  unsigned p0 = 0u, p1 = 2u; threefry(x0, y0, p0, p1);
  unsigned q0 = 1u, q1 = 3u; threefry(x0, y0, q0, q1);
  b0 = p1; b1 = q1;
}

// round-1 key histogram (hi16) + per-wave two smallest round-2 (key,pos) -> wave2[]
__global__ void k_tf1(unsigned* __restrict__ bucketA, unsigned long long* __restrict__ wave2){
  int q = blockIdx.x * 256 + threadIdx.x;
  bool valid = (q < NHALF);
  unsigned a0, a1, b0, b1; get_subkeys(a0, a1, b0, b1);
  unsigned long long m1 = ~0ull, m2 = ~0ull;
  if (valid){
    unsigned xa0 = (unsigned)q, xa1 = (unsigned)(q + NHALF); threefry(a0, a1, xa0, xa1);
    atomicAdd(&bucketA[xa0 >> 16], 1u);
    atomicAdd(&bucketA[xa1 >> 16], 1u);
    unsigned xb0 = (unsigned)q, xb1 = (unsigned)(q + NHALF); threefry(b0, b1, xb0, xb1);
    unsigned long long p0 = (((unsigned long long)xb0) << 32) | (unsigned)q;
    unsigned long long p1 = (((unsigned long long)xb1) << 32) | (unsigned)(q + NHALF);
    m1 = p0 < p1 ? p0 : p1;
    m2 = p0 < p1 ? p1 : p0;
  }
  #pragma unroll
  for (int off = 32; off > 0; off >>= 1){
    unsigned long long o1 = __shfl_xor(m1, off);
    unsigned long long o2 = __shfl_xor(m2, off);
    unsigned long long lo  = m1 < o1 ? m1 : o1;
    unsigned long long hi  = m1 < o1 ? o1 : m1;
    unsigned long long mn2 = m2 < o2 ? m2 : o2;
    m1 = lo;
    m2 = hi < mn2 ? hi : mn2;
  }
  if ((threadIdx.x & 63) == 0){
    int gw = blockIdx.x * 4 + (threadIdx.x >> 6);
    wave2[2 * gw]     = m1;
    wave2[2 * gw + 1] = m2;
  }
}

// one block: global two smallest (stable) -> target ranks j0,j1; then bucket+rank in keysA
__global__ __launch_bounds__(1024) void k_rank2(const unsigned long long* __restrict__ wave2,
                                                const unsigned* __restrict__ bucketA,
                                                unsigned* __restrict__ rankinfo){
  __shared__ unsigned long long pairs[32];
  __shared__ unsigned swave[16];
  __shared__ unsigned tgt[2];
  int t = threadIdx.x;
  unsigned long long m1 = ~0ull, m2 = ~0ull;
  if (t < WAVE2_N) m1 = wave2[t];
  #pragma unroll
  for (int off = 32; off > 0; off >>= 1){
    unsigned long long o1 = __shfl_xor(m1, off);
    unsigned long long o2 = __shfl_xor(m2, off);
    unsigned long long lo  = m1 < o1 ? m1 : o1;
    unsigned long long hi  = m1 < o1 ? o1 : m1;
    unsigned long long mn2 = m2 < o2 ? m2 : o2;
    m1 = lo;
    m2 = hi < mn2 ? hi : mn2;
  }
  if ((t & 63) == 0){ pairs[(t >> 6) * 2] = m1; pairs[(t >> 6) * 2 + 1] = m2; }
  __syncthreads();
  if (t == 0){
    unsigned long long g1 = ~0ull, g2 = ~0ull;
    for (int i = 0; i < 32; ++i){
      unsigned long long x = pairs[i];
      if (x < g1){ g2 = g1; g1 = x; } else if (x < g2){ g2 = x; }
    }
    tgt[0] = (unsigned)(g1 & 0xFFFFFFFFull);
    tgt[1] = (unsigned)(g2 & 0xFFFFFFFFull);
  }
  __syncthreads();
  unsigned sum = 0;
  for (int k = 0; k < 64; k += 4){
    uint4 u = *(const uint4*)(bucketA + t * 64 + k);
    sum += u.x + u.y + u.z + u.w;
  }
  unsigned excl = scan1024(sum, swave, t);
  unsigned incl = excl + sum;
  for (int which = 0; which < 2; ++which){
    unsigned target = tgt[which];
    if (incl > target && excl <= target){
      unsigned c2 = excl;
      for (int k = 0; k < 64; ++k){
        unsigned vv = bucketA[t * 64 + k];
        if (c2 + vv > target){
          rankinfo[which * 2 + 0] = (unsigned)(t * 64 + k);
          rankinfo[which * 2 + 1] = target - c2;
          break;
        }
        c2 += vv;
      }
    }
  }
}

__global__ void k_cand(unsigned* __restrict__ rankinfo, unsigned long long* __restrict__ cand){
  int q = blockIdx.x * 256 + threadIdx.x;
  if (q >= NHALF) return;
  unsigned a0, a1, b0, b1; get_subkeys(a0, a1, b0, b1);
  unsigned xa0 = (unsigned)q, xa1 = (unsigned)(q + NHALF); threefry(a0, a1, xa0, xa1);
  unsigned keys[2] = { xa0, xa1 };
  unsigned pos[2]  = { (unsigned)q, (unsigned)(q + NHALF) };
  for (int l = 0; l < 2; ++l){
    unsigned long long pk = (((unsigned long long)keys[l]) << 32) | pos[l];
    if ((keys[l] >> 16) == rankinfo[0]){
      unsigned slot = atomicAdd(&rankinfo[4], 1u);
      if (slot < 512) cand[slot] = pk;
    }
    if ((keys[l] >> 16) == rankinfo[2]){
      unsigned slot = atomicAdd(&rankinfo[5], 1u);
      if (slot < 512) cand[512 + slot] = pk;
    }
  }
}

__global__ void k_pick(const unsigned* __restrict__ rankinfo, const unsigned long long* __restrict__ cand,
                       const float* __restrict__ masked, float* __restrict__ centers){
  __shared__ unsigned sel[2];
  int t = threadIdx.x;
  for (int which = 0; which < 2; ++which){
    unsigned n = rankinfo[4 + which]; if (n > 512) n = 512;
    unsigned r = rankinfo[which * 2 + 1];
    const unsigned long long* cd = cand + which * 512;
    if ((unsigned)t < n){
      unsigned long long me = cd[t];
      unsigned rank = 0;
      for (unsigned i = 0; i < n; ++i) rank += (cd[i] < me);
      if (rank == r) sel[which] = (unsigned)(me & 0xFFFFFFFFull);
    }
  }
  __syncthreads();
  if (t < 64){
    centers[t]      = masked[(size_t)sel[0] * 64 + t];
    centers[64 + t] = masked[(size_t)sel[1] * 64 + t];
  }
}

// ===================== labels (wave-per-point, coalesced) =====================
__global__ __launch_bounds__(256) void k_labels(const float* __restrict__ masked,
    const float* __restrict__ centers, unsigned char* __restrict__ lab){
  const int tid = threadIdx.x;
  const int a = tid & 63;
  const int wv = tid >> 6;
  const float c0v = centers[a], c1v = centers[64 + a];
  const int base = blockIdx.x * 16 + wv * 4;     // grid 3277 covers NTOT exactly
  for (int i = 0; i < 4; ++i){
    int t = base + i;
    if (t >= NTOT) break;
    float v = masked[(size_t)t * 64 + a];
    float u0 = v - c0v, u1 = v - c1v;
    float d0 = u0 * u0, d1 = u1 * u1;
    #pragma unroll
    for (int off = 32; off > 0; off >>= 1){
      d0 += __shfl_xor(d0, off);
      d1 += __shfl_xor(d1, off);
    }
    if (a == 0) lab[t] = (d1 < d0) ? (unsigned char)1 : (unsigned char)0;
  }
}

// ordered per-cluster compaction from label bytes
__global__ __launch_bounds__(1024) void k_lists(const unsigned char* __restrict__ lab,
    unsigned* __restrict__ list0, unsigned* __restrict__ list1, unsigned* __restrict__ cnt){
  __shared__ unsigned swave[16];
  int b = blockIdx.x, t = threadIdx.x;
  const unsigned char* lb = lab + (size_t)b * NSEL;
  int j0 = t * 7;
  unsigned n0 = 0, n1 = 0, bits = 0;
  for (int k = 0; k < 7; ++k){
    int j = j0 + k; if (j >= NSEL) break;
    unsigned l = lb[j];
    bits |= l << k; n1 += l; n0 += 1u - l;
  }
  unsigned excl = scan1024(n0 | (n1 << 16), swave, t);
  unsigned g0 = excl & 0xFFFFu, g1 = excl >> 16;
  if (t == 1023){ cnt[b] = g0 + n0; cnt[8 + b] = g1 + n1; }
  for (int k = 0; k < 7; ++k){
    int j = j0 + k; if (j >= NSEL) break;
    if ((bits >> k) & 1u) list1[(size_t)b * NSEL + g1++] = (unsigned)j;
    else                  list0[(size_t)b * NSEL + g0++] = (unsigned)j;
  }
}

__device__ __forceinline__ unsigned compute_ms(const unsigned* cnt){
  unsigned m0 = 0, m1 = 0;
  #pragma unroll
  for (int b = 0; b < 8; ++b){
    m0 = cnt[b]     > m0 ? cnt[b]     : m0;
    m1 = cnt[8 + b] > m1 ? cnt[8 + b] : m1;
  }
  return m0 < m1 ? m0 : m1;
}

// ===================== decoder L1 loss (wave-per-pair) =====================
__global__ __launch_bounds__(256, 2) void k_loss(const float* __restrict__ masked,
    const unsigned* __restrict__ list0, const unsigned* __restrict__ list1,
    const unsigned* __restrict__ cnt,
    const float* __restrict__ dw1, const float* __restrict__ db1,
    const float* __restrict__ dw2, const float* __restrict__ db2,
    double* __restrict__ partial){
  __shared__ float w1t[64 * 129];   // w1t[c*129+k] = dw1[k][c], padded stride
  __shared__ float w2t[128 * 65];   // w2t[k*65+e]  = dw2[e][k], padded stride
  const int tid = threadIdx.x;
  for (int i = tid; i < 8192; i += 256){ int k = i >> 6, c = i & 63;  w1t[c * 129 + k] = dw1[i]; }
  for (int i = tid; i < 8192; i += 256){ int e = i >> 7, k2 = i & 127; w2t[k2 * 65 + e] = dw2[i]; }
  __syncthreads();
  const int wv = tid >> 6, a = tid & 63;
  const float h0b = db1[a], h1b = db1[a + 64], ob = db2[a];
  const unsigned ms = compute_ms(cnt);
  const int gw = blockIdx.x * 4 + wv;
  double acc = 0.0;
  for (int it = 0; it < 26; ++it){
    int t = gw + it * (LOSS_BLOCKS * 4);
    if (t >= NTOT) continue;                 // wave-uniform
    int b = t / NSEL, j = t - b * NSEL;
    if ((unsigned)j >= ms) continue;         // wave-uniform
    float x1 = 0.f, x2 = 0.f;
    if ((unsigned)j < cnt[b])     x1 = masked[((size_t)b * NSEL + list0[(size_t)b * NSEL + j]) * 64 + a];
    if ((unsigned)j < cnt[8 + b]) x2 = masked[((size_t)b * NSEL + list1[(size_t)b * NSEL + j]) * 64 + a];
    #pragma unroll
    for (int dir = 0; dir < 2; ++dir){
      float xin  = dir ? x1 : x2;   // decoder input
      float xcmp = dir ? x2 : x1;   // compare target
      float h0 = h0b, h1 = h1b;
      #pragma unroll
      for (int c = 0; c < 64; ++c){
        float xv = __shfl(xin, c);
        h0 = fmaf(w1t[c * 129 + a],      xv, h0);
        h1 = fmaf(w1t[c * 129 + 64 + a], xv, h1);
      }
      h0 = fmaxf(h0, 0.f); h1 = fmaxf(h1, 0.f);
      float o = ob;
      #pragma unroll
      for (int k = 0; k < 64; ++k){
        float hA = __shfl(h0, k);
        float hB = __shfl(h1, k);
        o = fmaf(w2t[k * 65 + a],        hA, o);
        o = fmaf(w2t[(k + 64) * 65 + a], hB, o);
      }
      acc += (double)fabsf(o - xcmp);
    }
  }
  for (int off = 32; off > 0; off >>= 1) acc += __shfl_down(acc, off);
  if (a == 0) partial[blockIdx.x * 4 + wv] = acc;
}

__global__ __launch_bounds__(1024) void k_final(const double* __restrict__ partial,
                        const unsigned* __restrict__ cnt, float* __restrict__ out){
  __shared__ double s[1024];
  int t = threadIdx.x;
  double a = partial[t] + partial[t + 1024];
  s[t] = a; __syncthreads();
  for (int off = 512; off > 0; off >>= 1){
    if (t < off) s[t] += s[t + off];
    __syncthreads();
  }
  if (t == 0){
    unsigned ms = compute_ms(cnt);
    double denom = 512.0 * (double)ms;   // B*ATTR*ms
    out[0] = (float)(ms ? s[0] / denom : 0.0);
  }
}

// ===================== launch =====================
extern "C" void kernel_launch(void* const* d_in, const int* in_sizes, int n_in,
                              void* d_out, int out_size, void* d_ws, size_t ws_size,
                              hipStream_t stream){
  (void)in_sizes; (void)n_in; (void)out_size; (void)ws_size;
  const float* Fe  = (const float*)d_in[0];
  const float* w1  = (const float*)d_in[2];
  const float* b1  = (const float*)d_in[3];
  const float* w2  = (const float*)d_in[4];
  const float* b2  = (const float*)d_in[5];
  const float* dw1 = (const float*)d_in[6];
  const float* db1 = (const float*)d_in[7];
  const float* dw2 = (const float*)d_in[8];
  const float* db2 = (const float*)d_in[9];
  float* out = (float*)d_out;
  char* ws = (char*)d_ws;

  float*              bnd      = (float*)(ws + OFF_BND);
  unsigned*           hist_hi  = (unsigned*)(ws + OFF_HIST_HI);
  unsigned*           bucketA  = (unsigned*)(ws + OFF_BUCKETA);
  unsigned*           rankinfo = (unsigned*)(ws + OFF_RANKINFO);
  unsigned long long* wave2    = (unsigned long long*)(ws + OFF_WAVE2);
  unsigned char*      lab      = (unsigned char*)(ws + OFF_LAB);
  unsigned short*     selpos   = (unsigned short*)(ws + OFF_SELPOS);
  unsigned*           cnt      = (unsigned*)(ws + OFF_CNT);
  float*              centers  = (float*)(ws + OFF_CENTERS);
  unsigned long long* cand     = (unsigned long long*)(ws + OFF_CAND);
  unsigned*           list0    = (unsigned*)(ws + OFF_LIST0);
  unsigned*           list1    = (unsigned*)(ws + OFF_LIST1);
  double*             partial  = (double*)(ws + OFF_PARTIAL);
  __half*             Xg       = (__half*)(ws + OFF_XG);
  float*              masked   = (float*)(ws + OFF_MASKED);

  k_init<<<dim3((ZERO_WORDS + 255) / 256), dim3(256), 0, stream>>>(ws);
  k_bnd<<<dim3(B_N * (H_N / 4)), dim3(256), 0, stream>>>(Fe, bnd, hist_hi);
  k_select<<<dim3(B_N), dim3(1024), 0, stream>>>(bnd, hist_hi, selpos);
  k_gather<<<dim3(HW_N / 1024, C_N / 4, B_N), dim3(256), 0, stream>>>(Fe, selpos, Xg);
  k_mlp<<<dim3((NTOT + 63) / 64), dim3(256), 0, stream>>>(Xg, w1, b1, w2, b2, masked);
  k_tf1<<<dim3(TF_BLOCKS), dim3(256), 0, stream>>>(bucketA, wave2);
  k_rank2<<<dim3(1), dim3(1024), 0, stream>>>(wave2, bucketA, rankinfo);
  k_cand<<<dim3(TF_BLOCKS), dim3(256), 0, stream>>>(rankinfo, cand);
  k_pick<<<dim3(1), dim3(256), 0, stream>>>(rankinfo, cand, masked, centers);
  k_labels<<<dim3((NTOT + 15) / 16), dim3(256), 0, stream>>>(masked, centers, lab);
  k_lists<<<dim3(B_N), dim3(1024), 0, stream>>>(lab, list0, list1, cnt);
  k_loss<<<dim3(LOSS_BLOCKS), dim3(256), 0, stream>>>(masked, list0, list1, cnt,
                                                      dw1, db1, dw2, db2, partial);
  k_final<<<dim3(1), dim3(1024), 0, stream>>>(partial, cnt, out);
}